// Round 10
// baseline (520.659 us; speedup 1.0000x reference)
//
#include <hip/hip_runtime.h>
#include <hip/hip_bf16.h>
#include <stdint.h>

// Problem constants
#define B_   8192
#define D_   2048
#define H_   4096
#define NCAT 1152   // real rows of concatenated head-weight matrix
#define NPAD 1280   // heads GEMM N padded to 5x256 tiles (phantom rows never stored)
#define NOUT 1044   // real output columns: 18 dirs + 1024 anchor + 1 progress + 1 critic

typedef float  f32x4   __attribute__((ext_vector_type(4)));
typedef __bf16 bf16x8  __attribute__((ext_vector_type(8)));
typedef __bf16 bf16x4  __attribute__((ext_vector_type(4)));

typedef const void __attribute__((address_space(1)))* gptr_t;
typedef void __attribute__((address_space(3)))*       lptr_t;

// ---------------- workspace layout (bytes) ----------------
#define XB_OFF    ((size_t)0)                      // x as bf16       [8192][2048]  33554432
#define S1_OFF    ((size_t)33554432)               // sign(W1) bf16   [4096][2048]  16777216
#define S2_OFF    ((size_t)50331648)               // sign(W2) bf16   [4096][4096]  33554432
#define WCAT_OFF  ((size_t)83886080)               // concat head W   [1152][4096]   9437184
#define BCAT_OFF  ((size_t)93323264)               // concat bias fp32 [1152]           4608
#define SCAT_OFF  ((size_t)93327872)               // per-col scale    [1152]           4608
#define H1_OFF    ((size_t)93332480)               // h1 bf16         [8192][4096]  67108864
#define H2_OFF    ((size_t)160441344)              // h2 bf16         [8192][4096]  67108864
#define P1_OFF    ((size_t)227550208)              // partial sums     [768] f32 (0-511 W2, 512-767 W1)
#define P2_OFF    ((size_t)227553280)              // partial (cnt,ms) [768] f32x2
#define SCAL_OFF  ((size_t)227559424)              // {delta1,alpha1,delta2,alpha2}
// NOTE: heads GEMM B-staging reads wcat rows 1152..1279 = 1 MB past WCAT end,
// landing in BCAT/SCAT/H1 (all finite). Never stored (col<NOUT guard) -> safe.

// ---------------- helpers ----------------
__device__ __forceinline__ float blockReduceSum(float v, float* sh4) {
  #pragma unroll
  for (int o = 32; o > 0; o >>= 1) v += __shfl_down(v, o, 64);
  const int lane = threadIdx.x & 63, wave = threadIdx.x >> 6;
  if (lane == 0) sh4[wave] = v;
  __syncthreads();
  float r = sh4[0] + sh4[1] + sh4[2] + sh4[3];
  __syncthreads();
  return r;
}

// ---------------- prepass A: cvt x->bf16 + absum(W1) + absum(W2), one launch ----------------
__global__ __launch_bounds__(256) void prepassA_k(const float* __restrict__ x,
                                                  __bf16* __restrict__ xb,
                                                  const float* __restrict__ W1,
                                                  const float* __restrict__ W2,
                                                  float* __restrict__ p1) {
  __shared__ float sh4[4];
  const int b = blockIdx.x;
  if (b < 512) {            // absum W2 -> p1[0..511]
    float s = 0.f;
    const int n4 = (H_ * H_) / 4;
    for (int i = b * 256 + threadIdx.x; i < n4; i += 512 * 256) {
      f32x4 w = ((const f32x4*)W2)[i];
      s += fabsf(w[0]) + fabsf(w[1]) + fabsf(w[2]) + fabsf(w[3]);
    }
    float t = blockReduceSum(s, sh4);
    if (threadIdx.x == 0) p1[b] = t;
  } else if (b < 768) {     // absum W1 -> p1[512..767]
    float s = 0.f;
    const int n4 = (H_ * D_) / 4;
    for (int i = (b - 512) * 256 + threadIdx.x; i < n4; i += 256 * 256) {
      f32x4 w = ((const f32x4*)W1)[i];
      s += fabsf(w[0]) + fabsf(w[1]) + fabsf(w[2]) + fabsf(w[3]);
    }
    float t = blockReduceSum(s, sh4);
    if (threadIdx.x == 0) p1[b] = t;
  } else {                  // cvt x (1280 blocks)
    const int n4 = (B_ * D_) / 4;
    for (int i = (b - 768) * 256 + threadIdx.x; i < n4; i += 1280 * 256) {
      f32x4 w = ((const f32x4*)x)[i];
      bf16x4 o;
      o[0] = (__bf16)w[0]; o[1] = (__bf16)w[1]; o[2] = (__bf16)w[2]; o[3] = (__bf16)w[3];
      ((bf16x4*)xb)[i] = o;
    }
  }
}

__global__ __launch_bounds__(256) void finA_k(const float* __restrict__ p1,
                                              float* __restrict__ scal) {
  __shared__ float sh4[4];
  float t2 = blockReduceSum(p1[threadIdx.x] + p1[threadIdx.x + 256], sh4);
  float t1 = blockReduceSum(p1[512 + threadIdx.x], sh4);
  if (threadIdx.x == 0) {
    scal[2] = 0.7f * t2 / (float)(H_ * H_);   // delta2
    scal[0] = 0.7f * t1 / (float)(H_ * D_);   // delta1
  }
}

// ---------------- prepass B: masked_sign(W1,W2) + head quant + concat, one launch ----------------
__global__ __launch_bounds__(256) void prepassB_k(const float* __restrict__ W1,
                                                  const float* __restrict__ W2,
                                                  const float* __restrict__ scal,
                                                  float2* __restrict__ p2,
                                                  __bf16* __restrict__ s1,
                                                  __bf16* __restrict__ s2,
                                                  const float* __restrict__ Wd,
                                                  const float* __restrict__ bd,
                                                  const float* __restrict__ Wa,
                                                  const float* __restrict__ Wp,
                                                  const float* __restrict__ Wc,
                                                  const float* __restrict__ ba,
                                                  const float* __restrict__ bp,
                                                  const float* __restrict__ bc,
                                                  __bf16* __restrict__ wcat,
                                                  float* __restrict__ bcat,
                                                  float* __restrict__ scat) {
  __shared__ float sh4[4];
  const int b = blockIdx.x;
  if (b < 768) {           // fused masked stats + sign write (W2 blocks 0-511, W1 512-767)
    const float* W = (b < 512) ? W2 : W1;
    __bf16* out    = (b < 512) ? s2 : s1;
    const float delta = (b < 512) ? scal[2] : scal[0];
    const int n4   = (b < 512) ? (H_ * H_) / 4 : (H_ * D_) / 4;
    const int bb   = (b < 512) ? b : b - 512;
    const int nblk = (b < 512) ? 512 : 256;
    float c = 0.f, s = 0.f;
    for (int i = bb * 256 + threadIdx.x; i < n4; i += nblk * 256) {
      f32x4 w = ((const f32x4*)W)[i];
      bf16x4 o;
      #pragma unroll
      for (int j = 0; j < 4; ++j) {
        float wv = w[j], a = fabsf(wv);
        bool m = (a > delta);
        if (m) { c += 1.f; s += a; }
        o[j] = (__bf16)(m ? (wv > 0.f ? 1.f : -1.f) : 0.f);
      }
      ((bf16x4*)out)[i] = o;
    }
    float tc = blockReduceSum(c, sh4);
    float ts = blockReduceSum(s, sh4);
    if (threadIdx.x == 0) p2[b] = make_float2(tc, ts);
  } else if (b < 774) {    // per-head quant of Wd (6 blocks)
    const int k = b - 768;
    const float* W = Wd + (size_t)k * 3 * H_;
    const int n = 3 * H_;
    float s = 0.f;
    for (int i = threadIdx.x; i < n; i += 256) s += fabsf(W[i]);
    float tot = blockReduceSum(s, sh4);
    const float delta = 0.7f * tot / (float)n;
    float c = 0.f, ms = 0.f;
    for (int i = threadIdx.x; i < n; i += 256) {
      float a = fabsf(W[i]);
      if (a > delta) { c += 1.f; ms += a; }
    }
    float tc = blockReduceSum(c, sh4);
    float tms = blockReduceSum(ms, sh4);
    const float alpha = tms / fmaxf(tc, 1.f);
    for (int i = threadIdx.x; i < n; i += 256) {
      float wv = W[i], a = fabsf(wv);
      float q = (a > delta) ? (wv > 0.f ? 1.f : -1.f) : 0.f;
      wcat[(size_t)(k * 3) * H_ + i] = (__bf16)q;
    }
    if (threadIdx.x < 3) {
      bcat[k * 3 + threadIdx.x] = bd[k * 3 + threadIdx.x];
      scat[k * 3 + threadIdx.x] = alpha;
    }
  } else if (b < 1286) {   // build_cat rows 18..1151 (grid-stride, 512 blocks)
    const int tot = 1134 * 1024;
    for (int idx = (b - 774) * 256 + threadIdx.x; idx < tot; idx += 512 * 256) {
      const int r = 18 + (idx >> 10);
      const int c4 = (idx & 1023) << 2;
      f32x4 w;
      if (r < 1042)       w = *(const f32x4*)(Wa + (size_t)(r - 18) * H_ + c4);
      else if (r == 1042) w = *(const f32x4*)(Wp + c4);
      else if (r == 1043) w = *(const f32x4*)(Wc + c4);
      else                w = (f32x4){0.f, 0.f, 0.f, 0.f};
      bf16x4 o;
      o[0] = (__bf16)w[0]; o[1] = (__bf16)w[1]; o[2] = (__bf16)w[2]; o[3] = (__bf16)w[3];
      *(bf16x4*)(wcat + (size_t)r * H_ + c4) = o;
    }
  } else {                 // fill bcat/scat rows 18..1151 (1 block)
    for (int i = threadIdx.x; i < NCAT - 18; i += 256) {
      const int r = 18 + i;
      float v = 0.f;
      if (r < 1042)       v = ba[r - 18];
      else if (r == 1042) v = bp[0];
      else if (r == 1043) v = bc[0];
      bcat[r] = v;
      scat[r] = 1.f;
    }
  }
}

__global__ __launch_bounds__(256) void finB_k(const float2* __restrict__ p2,
                                              float* __restrict__ scal) {
  __shared__ float sh4[4];
  float2 a = p2[threadIdx.x], bq = p2[threadIdx.x + 256];
  float tc2 = blockReduceSum(a.x + bq.x, sh4);
  float ts2 = blockReduceSum(a.y + bq.y, sh4);
  float2 w1 = p2[512 + threadIdx.x];
  float tc1 = blockReduceSum(w1.x, sh4);
  float ts1 = blockReduceSum(w1.y, sh4);
  if (threadIdx.x == 0) {
    scal[3] = ts2 / fmaxf(tc2, 1.f);   // alpha2
    scal[1] = ts1 / fmaxf(tc1, 1.f);   // alpha1
  }
}

// =================================================================================
// 256x256 GEMM v7: SINGLE region per K-tile (1 barrier, was 2). Round-9 analysis:
// wall = 4050 cyc/CU/K-tile vs MFMA floor 2483 and LDS floor ~2000-3000 — the gap
// is per-barrier full-block resync (2x per K-tile). v7 merges R1+R2:
//   region(t): read a0,b0 (12); stage A0,B0(t+1); MQ(0,0); read b1 (4); MQ(0,1);
//              read a1 (8, reg-WAR after MQ(0,*) — v3'-proven); stage A1,B1(t+1);
//              MQ(1,0); MQ(1,1); VM0(if staged); sched_barrier; s_barrier.
// Ledger (trivial): region entry has 0 outstanding vm loads; 8 issued, 8 retired
// by the end-of-region VM0. Unlike the m97 disease, the drain comes ~1240+ cyc of
// MFMA after the last stage issue (vs ~200-500 cyc L2-warm latency) -> ~0 stall.
// RAW: tile t fully landed (prev region VM0+barrier, all waves). LDS WAR: buf^1's
// reads are lgkm-retired by their consuming MFMAs before the prior barrier.
// MFMA shape stays 16x16x32 (round-8: 32x32 port -> 2.5e7 bank conflicts, reverted).
// Epilogue: round-7 direct store (round-9 LDS-coalesced store measured neutral).
// =================================================================================
#define VM0 asm volatile("s_waitcnt vmcnt(0)" ::: "memory")
#define SCHED0 __builtin_amdgcn_sched_barrier(0)
#define BARRIER __builtin_amdgcn_s_barrier()

#define RA_INTO(DST, BUF, QM) do {                                                    \
  const char* Ab_ = (const char*)&lds[BUF][0][QM][0][0];                              \
  _Pragma("unroll")                                                                   \
  for (int mf = 0; mf < 4; ++mf) {                                                    \
    DST[mf][0] = *(const bf16x8*)(Ab_ + aRow + mf * 2048 + kc0);                      \
    DST[mf][1] = *(const bf16x8*)(Ab_ + aRow + mf * 2048 + kc1);                      \
  }                                                                                   \
} while (0)

#define RB_INTO(DST, BUF, QN) do {                                                    \
  const char* Bb_ = (const char*)&lds[BUF][1][QN][0][0];                              \
  _Pragma("unroll")                                                                   \
  for (int nf = 0; nf < 2; ++nf) {                                                    \
    DST[nf][0] = *(const bf16x8*)(Bb_ + bRow + nf * 2048 + kc0);                      \
    DST[nf][1] = *(const bf16x8*)(Bb_ + bRow + nf * 2048 + kc1);                      \
  }                                                                                   \
} while (0)

#define MQ(QM, QN, BSET) do {                                                         \
  __builtin_amdgcn_s_setprio(1);                                                      \
  _Pragma("unroll")                                                                   \
  for (int mf = 0; mf < 4; ++mf)                                                      \
    _Pragma("unroll")                                                                 \
    for (int nf = 0; nf < 2; ++nf) {                                                  \
      acc[(QM) * 2 + (QN)][mf][nf] = __builtin_amdgcn_mfma_f32_16x16x32_bf16(         \
          aF[mf][0], BSET[nf][0], acc[(QM) * 2 + (QN)][mf][nf], 0, 0, 0);             \
      acc[(QM) * 2 + (QN)][mf][nf] = __builtin_amdgcn_mfma_f32_16x16x32_bf16(         \
          aF[mf][1], BSET[nf][1], acc[(QM) * 2 + (QN)][mf][nf], 0, 0, 0);             \
    }                                                                                 \
  __builtin_amdgcn_s_setprio(0);                                                      \
} while (0)

template <int EPI>
__global__ __launch_bounds__(512, 2) void gemm256_k(const __bf16* __restrict__ A,
                                                    const __bf16* __restrict__ Bm,
                                                    const float* __restrict__ scaleP,
                                                    const float* __restrict__ bias,
                                                    void* __restrict__ Cout,
                                                    int N, int K, int nbn) {
  __shared__ __attribute__((aligned(128))) __bf16 lds[2][2][2][128][64];
  const int tid = threadIdx.x;
  const int lane = tid & 63;
  const int wave = tid >> 6;
  const int wm2 = wave >> 2, wn2 = wave & 3;
  const int nwg = gridDim.x, cpx = nwg >> 3;            // XCD swizzle (grid % 8 == 0)
  const int bid = (blockIdx.x & 7) * cpx + (blockIdx.x >> 3);
  const int bm = bid / nbn, bn = bid % nbn;
  const int rowA0 = bm << 8, rowB0 = bn << 8;
  const int NT = K >> 6;                                // K-tiles of 64 (>=2)

  const int rl = lane & 15;
  const int ksel = (lane >> 4) << 4;
  const int swz = (rl & 7) << 4;                        // chunk-XOR swizzle
  const int kc0 = (0 + ksel) ^ swz;
  const int kc1 = (64 + ksel) ^ swz;
  const int aRow = (wm2 * 64 + rl) * 128;
  const int bRow = (wn2 * 32 + rl) * 128;

  f32x4 acc[4][4][2];
  #pragma unroll
  for (int q = 0; q < 4; ++q)
    #pragma unroll
    for (int m = 0; m < 4; ++m)
      #pragma unroll
      for (int n = 0; n < 2; ++n) acc[q][m][n] = (f32x4){0.f, 0.f, 0.f, 0.f};

  bf16x8 aF[4][2];    // current A-half fragments (half 0 then half 1, reg-WAR reuse)
  bf16x8 bQ0[2][2];   // b0 fragments (resident whole tile)
  bf16x8 bQ1[2][2];   // b1 fragments

  // hoisted per-thread global staging base pointers (8 total)
  const __bf16* gA_[2][2];
  const __bf16* gB_[2][2];
  #pragma unroll
  for (int hf = 0; hf < 2; ++hf)
    #pragma unroll
    for (int ld = 0; ld < 2; ++ld) {
      const int idx = ld * 512 + tid;
      const int row = idx >> 3;
      const int c16 = (idx & 7) ^ (row & 7);
      gA_[hf][ld] = A + (size_t)(rowA0 + hf * 128 + row) * K + c16 * 8;
      gB_[hf][ld] = Bm + (size_t)(rowB0 + hf * 128 + row) * K + c16 * 8;
    }

  auto stage_half = [&](int kt, int mat, int hf) {
    char* base = (char*)&lds[kt & 1][mat][hf][0][0];
    #pragma unroll
    for (int ld = 0; ld < 2; ++ld) {
      const int idx = ld * 512 + tid;
      const __bf16* g = (mat ? gB_[hf][ld] : gA_[hf][ld]) + kt * 64;
      __builtin_amdgcn_global_load_lds((gptr_t)g, (lptr_t)(base + idx * 16), 16, 0, 0);
    }
  };

  // prologue: stage tile0 fully; drain; barrier (cross-wave: all loads landed).
  stage_half(0, 0, 0); stage_half(0, 1, 0); stage_half(0, 0, 1); stage_half(0, 1, 1);
  VM0;
  SCHED0; BARRIER;

  for (int t = 0; t < NT; ++t) {
    const int buf = t & 1;
    const bool s1_ = (t + 1 < NT);
    // ---- single region ----
    RA_INTO(aF, buf, 0);                  // a0(t): 8 reads
    RB_INTO(bQ0, buf, 0);                 // b0(t): 4 reads
    if (s1_) { stage_half(t + 1, 0, 0); stage_half(t + 1, 1, 0); }   // A0,B0(t+1)
    MQ(0, 0, bQ0);
    RB_INTO(bQ1, buf, 1);                 // b1(t): 4 reads (consumed by MQ(0,1))
    MQ(0, 1, bQ1);
    RA_INTO(aF, buf, 1);                  // a1(t): 8 reads (reg WAR after MQ(0,*))
    if (s1_) { stage_half(t + 1, 0, 1); stage_half(t + 1, 1, 1); }   // A1,B1(t+1)
    MQ(1, 0, bQ0);
    MQ(1, 1, bQ1);
    if (s1_) VM0;                         // retire t+1's 8 loads (issued >=1240 cyc ago)
    SCHED0; BARRIER;
  }

  // epilogue (round-7 direct store)
  const int rj = (lane >> 4) << 2;
  if constexpr (EPI == 0) {
    __bf16* C = (__bf16*)Cout;
    const float s = scaleP[0];
    #pragma unroll
    for (int qm = 0; qm < 2; ++qm)
      #pragma unroll
      for (int qn = 0; qn < 2; ++qn)
        #pragma unroll
        for (int nf = 0; nf < 2; ++nf) {
          const int col = rowB0 + qn * 128 + wn2 * 32 + nf * 16 + rl;
          const float bv = bias[col];
          #pragma unroll
          for (int mf = 0; mf < 4; ++mf)
            #pragma unroll
            for (int j = 0; j < 4; ++j) {
              const int row = rowA0 + qm * 128 + wm2 * 64 + mf * 16 + rj + j;
              float v = acc[qm * 2 + qn][mf][nf][j] * s + bv;
              v = v > 0.f ? v : 0.f;
              C[(size_t)row * N + col] = (__bf16)v;
            }
        }
  } else {
    float* C = (float*)Cout;
    #pragma unroll
    for (int qm = 0; qm < 2; ++qm)
      #pragma unroll
      for (int qn = 0; qn < 2; ++qn)
        #pragma unroll
        for (int nf = 0; nf < 2; ++nf) {
          const int col = rowB0 + qn * 128 + wn2 * 32 + nf * 16 + rl;
          if (col < NOUT) {
            const float s = scaleP[col];
            const float bv = bias[col];
            #pragma unroll
            for (int mf = 0; mf < 4; ++mf)
              #pragma unroll
              for (int j = 0; j < 4; ++j) {
                const int row = rowA0 + qm * 128 + wm2 * 64 + mf * 16 + rj + j;
                float v = acc[qm * 2 + qn][mf][nf][j] * s + bv;
                if (col == NOUT - 1) v = 1.f / (1.f + __expf(-v));
                C[(size_t)row * NOUT + col] = v;
              }
          }
        }
  }
}

// ---------------- launch ----------------
extern "C" void kernel_launch(void* const* d_in, const int* in_sizes, int n_in,
                              void* d_out, int out_size, void* d_ws, size_t ws_size,
                              hipStream_t stream) {
  (void)in_sizes; (void)n_in; (void)out_size; (void)ws_size;
  const float* x  = (const float*)d_in[0];
  const float* W1 = (const float*)d_in[1];
  const float* b1 = (const float*)d_in[2];
  const float* W2 = (const float*)d_in[3];
  const float* b2 = (const float*)d_in[4];
  const float* Wd = (const float*)d_in[5];
  const float* bd = (const float*)d_in[6];
  const float* Wa = (const float*)d_in[7];
  const float* ba = (const float*)d_in[8];
  const float* Wp = (const float*)d_in[9];
  const float* bp = (const float*)d_in[10];
  const float* Wc = (const float*)d_in[11];
  const float* bc = (const float*)d_in[12];

  char* ws = (char*)d_ws;
  __bf16* xb   = (__bf16*)(ws + XB_OFF);
  __bf16* s1   = (__bf16*)(ws + S1_OFF);
  __bf16* s2   = (__bf16*)(ws + S2_OFF);
  __bf16* wcat = (__bf16*)(ws + WCAT_OFF);
  float*  bcat = (float*)(ws + BCAT_OFF);
  float*  scat = (float*)(ws + SCAT_OFF);
  __bf16* h1   = (__bf16*)(ws + H1_OFF);
  __bf16* h2   = (__bf16*)(ws + H2_OFF);
  float*  p1   = (float*)(ws + P1_OFF);
  float2* p2   = (float2*)(ws + P2_OFF);
  float*  scal = (float*)(ws + SCAL_OFF);

  // pre-passes: 4 launches
  prepassA_k<<<2048, 256, 0, stream>>>(x, xb, W1, W2, p1);
  finA_k<<<1, 256, 0, stream>>>(p1, scal);
  prepassB_k<<<1287, 256, 0, stream>>>(W1, W2, scal, p2, s1, s2, Wd, bd, Wa, Wp, Wc,
                                       ba, bp, bc, wcat, bcat, scat);
  finB_k<<<1, 256, 0, stream>>>(p2, scal);

  // layer 1: h1 = relu(alpha1*(x@S1^T) + b1)   [8192,2048]x[4096,2048]^T
  gemm256_k<0><<<(B_ / 256) * (H_ / 256), 512, 0, stream>>>(xb, s1, scal + 1, b1, h1, H_, D_, H_ / 256);
  // layer 2: h2 = relu(alpha2*(h1@S2^T) + b2)  [8192,4096]x[4096,4096]^T
  gemm256_k<0><<<(B_ / 256) * (H_ / 256), 512, 0, stream>>>(h1, s2, scal + 3, b2, h2, H_, H_, H_ / 256);
  // heads: out = scat[col]*(h2@Wcat^T) + bcat, sigmoid at col 1043, store col<1044;
  // N padded to 1280 (5x256 tiles); phantom B rows read finite ws garbage, never stored.
  gemm256_k<1><<<(B_ / 256) * (NPAD / 256), 512, 0, stream>>>(h2, wcat, scat, bcat, d_out, NPAD, H_, NPAD / 256);
}

// Round 11
// 480.219 us; speedup vs baseline: 1.0842x; 1.0842x over previous
//
#include <hip/hip_runtime.h>
#include <hip/hip_bf16.h>
#include <stdint.h>

// Problem constants
#define B_   8192
#define D_   2048
#define H_   4096
#define NCAT 1152   // real rows of concatenated head-weight matrix
#define NPAD 1280   // heads GEMM N padded to 5x256 tiles (phantom rows never stored)
#define NOUT 1044   // real output columns: 18 dirs + 1024 anchor + 1 progress + 1 critic

typedef float  f32x4   __attribute__((ext_vector_type(4)));
typedef __bf16 bf16x8  __attribute__((ext_vector_type(8)));
typedef __bf16 bf16x4  __attribute__((ext_vector_type(4)));

typedef const void __attribute__((address_space(1)))* gptr_t;
typedef void __attribute__((address_space(3)))*       lptr_t;

// ---------------- workspace layout (bytes) ----------------
#define XB_OFF    ((size_t)0)                      // x as bf16       [8192][2048]  33554432
#define S1_OFF    ((size_t)33554432)               // sign(W1) bf16   [4096][2048]  16777216
#define S2_OFF    ((size_t)50331648)               // sign(W2) bf16   [4096][4096]  33554432
#define WCAT_OFF  ((size_t)83886080)               // concat head W   [1152][4096]   9437184
#define BCAT_OFF  ((size_t)93323264)               // concat bias fp32 [1152]           4608
#define SCAT_OFF  ((size_t)93327872)               // per-col scale    [1152]           4608
#define H1_OFF    ((size_t)93332480)               // h1 bf16         [8192][4096]  67108864
#define H2_OFF    ((size_t)160441344)              // h2 bf16         [8192][4096]  67108864
#define P1_OFF    ((size_t)227550208)              // partial sums     [768] f32 (0-511 W2, 512-767 W1)
#define P2_OFF    ((size_t)227553280)              // partial (cnt,ms) [768] f32x2
#define SCAL_OFF  ((size_t)227559424)              // {delta1,alpha1,delta2,alpha2}
// NOTE: heads GEMM B-staging reads wcat rows 1152..1279 = 1 MB past WCAT end,
// landing in BCAT/SCAT/H1 (all finite). Never stored (col<NOUT guard) -> safe.

// ---------------- helpers ----------------
__device__ __forceinline__ float blockReduceSum(float v, float* sh4) {
  #pragma unroll
  for (int o = 32; o > 0; o >>= 1) v += __shfl_down(v, o, 64);
  const int lane = threadIdx.x & 63, wave = threadIdx.x >> 6;
  if (lane == 0) sh4[wave] = v;
  __syncthreads();
  float r = sh4[0] + sh4[1] + sh4[2] + sh4[3];
  __syncthreads();
  return r;
}

// ---------------- prepass A: cvt x->bf16 + absum(W1) + absum(W2), one launch ----------------
__global__ __launch_bounds__(256) void prepassA_k(const float* __restrict__ x,
                                                  __bf16* __restrict__ xb,
                                                  const float* __restrict__ W1,
                                                  const float* __restrict__ W2,
                                                  float* __restrict__ p1) {
  __shared__ float sh4[4];
  const int b = blockIdx.x;
  if (b < 512) {            // absum W2 -> p1[0..511]
    float s = 0.f;
    const int n4 = (H_ * H_) / 4;
    for (int i = b * 256 + threadIdx.x; i < n4; i += 512 * 256) {
      f32x4 w = ((const f32x4*)W2)[i];
      s += fabsf(w[0]) + fabsf(w[1]) + fabsf(w[2]) + fabsf(w[3]);
    }
    float t = blockReduceSum(s, sh4);
    if (threadIdx.x == 0) p1[b] = t;
  } else if (b < 768) {     // absum W1 -> p1[512..767]
    float s = 0.f;
    const int n4 = (H_ * D_) / 4;
    for (int i = (b - 512) * 256 + threadIdx.x; i < n4; i += 256 * 256) {
      f32x4 w = ((const f32x4*)W1)[i];
      s += fabsf(w[0]) + fabsf(w[1]) + fabsf(w[2]) + fabsf(w[3]);
    }
    float t = blockReduceSum(s, sh4);
    if (threadIdx.x == 0) p1[b] = t;
  } else {                  // cvt x (1280 blocks)
    const int n4 = (B_ * D_) / 4;
    for (int i = (b - 768) * 256 + threadIdx.x; i < n4; i += 1280 * 256) {
      f32x4 w = ((const f32x4*)x)[i];
      bf16x4 o;
      o[0] = (__bf16)w[0]; o[1] = (__bf16)w[1]; o[2] = (__bf16)w[2]; o[3] = (__bf16)w[3];
      ((bf16x4*)xb)[i] = o;
    }
  }
}

__global__ __launch_bounds__(256) void finA_k(const float* __restrict__ p1,
                                              float* __restrict__ scal) {
  __shared__ float sh4[4];
  float t2 = blockReduceSum(p1[threadIdx.x] + p1[threadIdx.x + 256], sh4);
  float t1 = blockReduceSum(p1[512 + threadIdx.x], sh4);
  if (threadIdx.x == 0) {
    scal[2] = 0.7f * t2 / (float)(H_ * H_);   // delta2
    scal[0] = 0.7f * t1 / (float)(H_ * D_);   // delta1
  }
}

// ---------------- prepass B: masked_sign(W1,W2) + head quant + concat, one launch ----------------
__global__ __launch_bounds__(256) void prepassB_k(const float* __restrict__ W1,
                                                  const float* __restrict__ W2,
                                                  const float* __restrict__ scal,
                                                  float2* __restrict__ p2,
                                                  __bf16* __restrict__ s1,
                                                  __bf16* __restrict__ s2,
                                                  const float* __restrict__ Wd,
                                                  const float* __restrict__ bd,
                                                  const float* __restrict__ Wa,
                                                  const float* __restrict__ Wp,
                                                  const float* __restrict__ Wc,
                                                  const float* __restrict__ ba,
                                                  const float* __restrict__ bp,
                                                  const float* __restrict__ bc,
                                                  __bf16* __restrict__ wcat,
                                                  float* __restrict__ bcat,
                                                  float* __restrict__ scat) {
  __shared__ float sh4[4];
  const int b = blockIdx.x;
  if (b < 768) {           // fused masked stats + sign write (W2 blocks 0-511, W1 512-767)
    const float* W = (b < 512) ? W2 : W1;
    __bf16* out    = (b < 512) ? s2 : s1;
    const float delta = (b < 512) ? scal[2] : scal[0];
    const int n4   = (b < 512) ? (H_ * H_) / 4 : (H_ * D_) / 4;
    const int bb   = (b < 512) ? b : b - 512;
    const int nblk = (b < 512) ? 512 : 256;
    float c = 0.f, s = 0.f;
    for (int i = bb * 256 + threadIdx.x; i < n4; i += nblk * 256) {
      f32x4 w = ((const f32x4*)W)[i];
      bf16x4 o;
      #pragma unroll
      for (int j = 0; j < 4; ++j) {
        float wv = w[j], a = fabsf(wv);
        bool m = (a > delta);
        if (m) { c += 1.f; s += a; }
        o[j] = (__bf16)(m ? (wv > 0.f ? 1.f : -1.f) : 0.f);
      }
      ((bf16x4*)out)[i] = o;
    }
    float tc = blockReduceSum(c, sh4);
    float ts = blockReduceSum(s, sh4);
    if (threadIdx.x == 0) p2[b] = make_float2(tc, ts);
  } else if (b < 774) {    // per-head quant of Wd (6 blocks)
    const int k = b - 768;
    const float* W = Wd + (size_t)k * 3 * H_;
    const int n = 3 * H_;
    float s = 0.f;
    for (int i = threadIdx.x; i < n; i += 256) s += fabsf(W[i]);
    float tot = blockReduceSum(s, sh4);
    const float delta = 0.7f * tot / (float)n;
    float c = 0.f, ms = 0.f;
    for (int i = threadIdx.x; i < n; i += 256) {
      float a = fabsf(W[i]);
      if (a > delta) { c += 1.f; ms += a; }
    }
    float tc = blockReduceSum(c, sh4);
    float tms = blockReduceSum(ms, sh4);
    const float alpha = tms / fmaxf(tc, 1.f);
    for (int i = threadIdx.x; i < n; i += 256) {
      float wv = W[i], a = fabsf(wv);
      float q = (a > delta) ? (wv > 0.f ? 1.f : -1.f) : 0.f;
      wcat[(size_t)(k * 3) * H_ + i] = (__bf16)q;
    }
    if (threadIdx.x < 3) {
      bcat[k * 3 + threadIdx.x] = bd[k * 3 + threadIdx.x];
      scat[k * 3 + threadIdx.x] = alpha;
    }
  } else if (b < 1286) {   // build_cat rows 18..1151 (grid-stride, 512 blocks)
    const int tot = 1134 * 1024;
    for (int idx = (b - 774) * 256 + threadIdx.x; idx < tot; idx += 512 * 256) {
      const int r = 18 + (idx >> 10);
      const int c4 = (idx & 1023) << 2;
      f32x4 w;
      if (r < 1042)       w = *(const f32x4*)(Wa + (size_t)(r - 18) * H_ + c4);
      else if (r == 1042) w = *(const f32x4*)(Wp + c4);
      else if (r == 1043) w = *(const f32x4*)(Wc + c4);
      else                w = (f32x4){0.f, 0.f, 0.f, 0.f};
      bf16x4 o;
      o[0] = (__bf16)w[0]; o[1] = (__bf16)w[1]; o[2] = (__bf16)w[2]; o[3] = (__bf16)w[3];
      *(bf16x4*)(wcat + (size_t)r * H_ + c4) = o;
    }
  } else {                 // fill bcat/scat rows 18..1151 (1 block)
    for (int i = threadIdx.x; i < NCAT - 18; i += 256) {
      const int r = 18 + i;
      float v = 0.f;
      if (r < 1042)       v = ba[r - 18];
      else if (r == 1042) v = bp[0];
      else if (r == 1043) v = bc[0];
      bcat[r] = v;
      scat[r] = 1.f;
    }
  }
}

__global__ __launch_bounds__(256) void finB_k(const float2* __restrict__ p2,
                                              float* __restrict__ scal) {
  __shared__ float sh4[4];
  float2 a = p2[threadIdx.x], bq = p2[threadIdx.x + 256];
  float tc2 = blockReduceSum(a.x + bq.x, sh4);
  float ts2 = blockReduceSum(a.y + bq.y, sh4);
  float2 w1 = p2[512 + threadIdx.x];
  float tc1 = blockReduceSum(w1.x, sh4);
  float ts1 = blockReduceSum(w1.y, sh4);
  if (threadIdx.x == 0) {
    scal[3] = ts2 / fmaxf(tc2, 1.f);   // alpha2
    scal[1] = ts1 / fmaxf(tc1, 1.f);   // alpha1
  }
}

// =================================================================================
// 256x256 GEMM v4 (round-7, BEST measured: 484 us total, G2 216 us / 1272 TF /
// MfmaUtil 57% / 0 bank conflicts). 2 regions per K-tile, counted vmcnt:
//   R1(t): read b1(t); MQ(0,0); MQ(0,1); read a1(t); stage A1,B1(t+1); VM4; bar
//   R2(t): MQ(1,0); MQ(1,1); read a0,b0(t+1); stage A0,B0(t+2); VM4|VM0-tail; bar
// Guarantee pattern: [stage][VM][barrier] -> reads in the NEXT region (vmcnt is
// per-wave; barrier after each wave's wait makes the collective half-tile safe).
// Structural attempts that did NOT beat this (all measured):
//   r8: 32x32x16 MFMA port -> 2.5e7 bank conflicts (lane>>5 chunk select), 524 us
//   r9: LDS-coalesced epilogue store -> neutral (store tail not critical), 488 us
//   r10: single barrier + in-region VM0 -> drain stall (T4 violation), 521 us
//   BK=32 for 2 blocks/CU: blocked — 64B LDS rows span 16 banks -> irreducible
//   8-way phase conflict under global_load_lds's linear-write constraint.
// =================================================================================
#define VM4 asm volatile("s_waitcnt vmcnt(4)" ::: "memory")
#define VM0 asm volatile("s_waitcnt vmcnt(0)" ::: "memory")
#define SCHED0 __builtin_amdgcn_sched_barrier(0)
#define BARRIER __builtin_amdgcn_s_barrier()

#define RA_INTO(DST, BUF, QM) do {                                                    \
  const char* Ab_ = (const char*)&lds[BUF][0][QM][0][0];                              \
  _Pragma("unroll")                                                                   \
  for (int mf = 0; mf < 4; ++mf) {                                                    \
    DST[mf][0] = *(const bf16x8*)(Ab_ + aRow + mf * 2048 + kc0);                      \
    DST[mf][1] = *(const bf16x8*)(Ab_ + aRow + mf * 2048 + kc1);                      \
  }                                                                                   \
} while (0)

#define RB_INTO(DST, BUF, QN) do {                                                    \
  const char* Bb_ = (const char*)&lds[BUF][1][QN][0][0];                              \
  _Pragma("unroll")                                                                   \
  for (int nf = 0; nf < 2; ++nf) {                                                    \
    DST[nf][0] = *(const bf16x8*)(Bb_ + bRow + nf * 2048 + kc0);                      \
    DST[nf][1] = *(const bf16x8*)(Bb_ + bRow + nf * 2048 + kc1);                      \
  }                                                                                   \
} while (0)

#define MQ(QM, QN, BSET) do {                                                         \
  __builtin_amdgcn_s_setprio(1);                                                      \
  _Pragma("unroll")                                                                   \
  for (int mf = 0; mf < 4; ++mf)                                                      \
    _Pragma("unroll")                                                                 \
    for (int nf = 0; nf < 2; ++nf) {                                                  \
      acc[(QM) * 2 + (QN)][mf][nf] = __builtin_amdgcn_mfma_f32_16x16x32_bf16(         \
          aF[mf][0], BSET[nf][0], acc[(QM) * 2 + (QN)][mf][nf], 0, 0, 0);             \
      acc[(QM) * 2 + (QN)][mf][nf] = __builtin_amdgcn_mfma_f32_16x16x32_bf16(         \
          aF[mf][1], BSET[nf][1], acc[(QM) * 2 + (QN)][mf][nf], 0, 0, 0);             \
    }                                                                                 \
  __builtin_amdgcn_s_setprio(0);                                                      \
} while (0)

template <int EPI>
__global__ __launch_bounds__(512, 2) void gemm256_k(const __bf16* __restrict__ A,
                                                    const __bf16* __restrict__ Bm,
                                                    const float* __restrict__ scaleP,
                                                    const float* __restrict__ bias,
                                                    void* __restrict__ Cout,
                                                    int N, int K, int nbn) {
  __shared__ __attribute__((aligned(128))) __bf16 lds[2][2][2][128][64];
  const int tid = threadIdx.x;
  const int lane = tid & 63;
  const int wave = tid >> 6;
  const int wm2 = wave >> 2, wn2 = wave & 3;
  const int nwg = gridDim.x, cpx = nwg >> 3;            // XCD swizzle (grid % 8 == 0)
  const int bid = (blockIdx.x & 7) * cpx + (blockIdx.x >> 3);
  const int bm = bid / nbn, bn = bid % nbn;
  const int rowA0 = bm << 8, rowB0 = bn << 8;
  const int NT = K >> 6;                                // K-tiles of 64 (even, >=2)

  const int rl = lane & 15;
  const int ksel = (lane >> 4) << 4;
  const int swz = (rl & 7) << 4;                        // chunk-XOR swizzle
  const int kc0 = (0 + ksel) ^ swz;
  const int kc1 = (64 + ksel) ^ swz;
  const int aRow = (wm2 * 64 + rl) * 128;
  const int bRow = (wn2 * 32 + rl) * 128;

  f32x4 acc[4][4][2];
  #pragma unroll
  for (int q = 0; q < 4; ++q)
    #pragma unroll
    for (int m = 0; m < 4; ++m)
      #pragma unroll
      for (int n = 0; n < 2; ++n) acc[q][m][n] = (f32x4){0.f, 0.f, 0.f, 0.f};

  bf16x8 aF[4][2];    // current A-half fragments (QM0 in R1, QM1 in R2)
  bf16x8 bQ0[2][2];   // b0 fragments (resident whole tile)
  bf16x8 bQ1[2][2];   // b1 fragments

  // hoisted per-thread global staging base pointers (8 total)
  const __bf16* gA_[2][2];
  const __bf16* gB_[2][2];
  #pragma unroll
  for (int hf = 0; hf < 2; ++hf)
    #pragma unroll
    for (int ld = 0; ld < 2; ++ld) {
      const int idx = ld * 512 + tid;
      const int row = idx >> 3;
      const int c16 = (idx & 7) ^ (row & 7);
      gA_[hf][ld] = A + (size_t)(rowA0 + hf * 128 + row) * K + c16 * 8;
      gB_[hf][ld] = Bm + (size_t)(rowB0 + hf * 128 + row) * K + c16 * 8;
    }

  auto stage_half = [&](int kt, int mat, int hf) {
    char* base = (char*)&lds[kt & 1][mat][hf][0][0];
    #pragma unroll
    for (int ld = 0; ld < 2; ++ld) {
      const int idx = ld * 512 + tid;
      const __bf16* g = (mat ? gB_[hf][ld] : gA_[hf][ld]) + kt * 64;
      __builtin_amdgcn_global_load_lds((gptr_t)g, (lptr_t)(base + idx * 16), 16, 0, 0);
    }
  };

  // prologue: tile0 fully + tile1 A0,B0; VM4 (retires tile0) BEFORE barrier;
  // reads after barrier (cross-wave safe).
  stage_half(0, 0, 0); stage_half(0, 1, 0); stage_half(0, 0, 1); stage_half(0, 1, 1);
  stage_half(1, 0, 0); stage_half(1, 1, 0);
  VM4;
  SCHED0; BARRIER;
  RA_INTO(aF, 0, 0);
  RB_INTO(bQ0, 0, 0);

  for (int t = 0; t < NT; ++t) {
    const int buf = t & 1;
    const bool s1_ = (t + 1 < NT), s2_ = (t + 2 < NT);
    // ---- R1 ----
    RB_INTO(bQ1, buf, 1);                 // b1(t): landed (prev region VM + barrier)
    MQ(0, 0, bQ0);
    MQ(0, 1, bQ1);
    RA_INTO(aF, buf, 1);                  // a1(t) (reg WAR after MFMA issue)
    if (s1_) {
      stage_half(t + 1, 0, 1); stage_half(t + 1, 1, 1);
      VM4;                                // retire A0,B0(t+1) -> R2 reads safe
    }
    SCHED0; BARRIER;
    // ---- R2 ----
    MQ(1, 0, bQ0);
    MQ(1, 1, bQ1);
    if (s1_) {
      RA_INTO(aF, buf ^ 1, 0);            // a0(t+1)
      RB_INTO(bQ0, buf ^ 1, 0);           // b0(t+1)
      if (s2_) {
        stage_half(t + 2, 0, 0); stage_half(t + 2, 1, 0);
        VM4;                              // retire A1,B1(t+1) -> next R1 reads safe
      } else {
        VM0;                              // tail t=NT-2: drain A1,B1(NT-1)
      }
    }
    SCHED0; BARRIER;
  }

  // epilogue
  const int rj = (lane >> 4) << 2;
  if constexpr (EPI == 0) {
    __bf16* C = (__bf16*)Cout;
    const float s = scaleP[0];
    #pragma unroll
    for (int qm = 0; qm < 2; ++qm)
      #pragma unroll
      for (int qn = 0; qn < 2; ++qn)
        #pragma unroll
        for (int nf = 0; nf < 2; ++nf) {
          const int col = rowB0 + qn * 128 + wn2 * 32 + nf * 16 + rl;
          const float bv = bias[col];
          #pragma unroll
          for (int mf = 0; mf < 4; ++mf)
            #pragma unroll
            for (int j = 0; j < 4; ++j) {
              const int row = rowA0 + qm * 128 + wm2 * 64 + mf * 16 + rj + j;
              float v = acc[qm * 2 + qn][mf][nf][j] * s + bv;
              v = v > 0.f ? v : 0.f;
              C[(size_t)row * N + col] = (__bf16)v;
            }
        }
  } else {
    float* C = (float*)Cout;
    #pragma unroll
    for (int qm = 0; qm < 2; ++qm)
      #pragma unroll
      for (int qn = 0; qn < 2; ++qn)
        #pragma unroll
        for (int nf = 0; nf < 2; ++nf) {
          const int col = rowB0 + qn * 128 + wn2 * 32 + nf * 16 + rl;
          if (col < NOUT) {
            const float s = scaleP[col];
            const float bv = bias[col];
            #pragma unroll
            for (int mf = 0; mf < 4; ++mf)
              #pragma unroll
              for (int j = 0; j < 4; ++j) {
                const int row = rowA0 + qm * 128 + wm2 * 64 + mf * 16 + rj + j;
                float v = acc[qm * 2 + qn][mf][nf][j] * s + bv;
                if (col == NOUT - 1) v = 1.f / (1.f + __expf(-v));
                C[(size_t)row * NOUT + col] = v;
              }
          }
        }
  }
}

// ---------------- launch ----------------
extern "C" void kernel_launch(void* const* d_in, const int* in_sizes, int n_in,
                              void* d_out, int out_size, void* d_ws, size_t ws_size,
                              hipStream_t stream) {
  (void)in_sizes; (void)n_in; (void)out_size; (void)ws_size;
  const float* x  = (const float*)d_in[0];
  const float* W1 = (const float*)d_in[1];
  const float* b1 = (const float*)d_in[2];
  const float* W2 = (const float*)d_in[3];
  const float* b2 = (const float*)d_in[4];
  const float* Wd = (const float*)d_in[5];
  const float* bd = (const float*)d_in[6];
  const float* Wa = (const float*)d_in[7];
  const float* ba = (const float*)d_in[8];
  const float* Wp = (const float*)d_in[9];
  const float* bp = (const float*)d_in[10];
  const float* Wc = (const float*)d_in[11];
  const float* bc = (const float*)d_in[12];

  char* ws = (char*)d_ws;
  __bf16* xb   = (__bf16*)(ws + XB_OFF);
  __bf16* s1   = (__bf16*)(ws + S1_OFF);
  __bf16* s2   = (__bf16*)(ws + S2_OFF);
  __bf16* wcat = (__bf16*)(ws + WCAT_OFF);
  float*  bcat = (float*)(ws + BCAT_OFF);
  float*  scat = (float*)(ws + SCAT_OFF);
  __bf16* h1   = (__bf16*)(ws + H1_OFF);
  __bf16* h2   = (__bf16*)(ws + H2_OFF);
  float*  p1   = (float*)(ws + P1_OFF);
  float2* p2   = (float2*)(ws + P2_OFF);
  float*  scal = (float*)(ws + SCAL_OFF);

  // pre-passes: 4 launches
  prepassA_k<<<2048, 256, 0, stream>>>(x, xb, W1, W2, p1);
  finA_k<<<1, 256, 0, stream>>>(p1, scal);
  prepassB_k<<<1287, 256, 0, stream>>>(W1, W2, scal, p2, s1, s2, Wd, bd, Wa, Wp, Wc,
                                       ba, bp, bc, wcat, bcat, scat);
  finB_k<<<1, 256, 0, stream>>>(p2, scal);

  // layer 1: h1 = relu(alpha1*(x@S1^T) + b1)   [8192,2048]x[4096,2048]^T
  gemm256_k<0><<<(B_ / 256) * (H_ / 256), 512, 0, stream>>>(xb, s1, scal + 1, b1, h1, H_, D_, H_ / 256);
  // layer 2: h2 = relu(alpha2*(h1@S2^T) + b2)  [8192,4096]x[4096,4096]^T
  gemm256_k<0><<<(B_ / 256) * (H_ / 256), 512, 0, stream>>>(h1, s2, scal + 3, b2, h2, H_, H_, H_ / 256);
  // heads: out = scat[col]*(h2@Wcat^T) + bcat, sigmoid at col 1043, store col<1044;
  // N padded to 1280 (5x256 tiles); phantom B rows read finite ws garbage, never stored.
  gemm256_k<1><<<(B_ / 256) * (NPAD / 256), 512, 0, stream>>>(h2, wcat, scat, bcat, d_out, NPAD, H_, NPAD / 256);
}